// Round 2
// baseline (971.720 us; speedup 1.0000x reference)
//
#include <hip/hip_runtime.h>

// TBE pooled-sum forward, v2: latency-optimized gather.
// weights: [T, E, D] fp32; indices: [T*B*L] int32; offsets: [T*B+1] int32.
// out[b, t*D+d] = sum_{i in bag(t,b)} weights[t, idx[i], d].
//
// One wave per bag. Indices for the whole bag are prefetched with ONE
// coalesced load (lane j <- indices[start+j]) and broadcast via __shfl, so
// the gather loop is a pure vmem stream (no interleaved index loads -> no
// forced vmcnt(0) drains mid-chain). Per-lane float4 (16B), half-wave per
// row: each wave instruction gathers TWO 512B rows (1KB). Chunks of 8 rows
// keep 4 independent 1KB loads in flight per wave.

constexpr int T = 16;
constexpr int E = 100000;
constexpr int D = 128;
constexpr int BPT = 4096;                 // bags per table (power of 2)
constexpr int NUM_BAGS = T * BPT;         // 65536
constexpr int WAVES_PER_BLOCK = 4;        // block = 256

__device__ inline void add4(float4& a, const float4& v) {
    a.x += v.x; a.y += v.y; a.z += v.z; a.w += v.w;
}

__global__ __launch_bounds__(256) void tbe_pool_kernel(
    const float* __restrict__ weights,
    const int* __restrict__ indices,
    const int* __restrict__ offsets,
    float* __restrict__ out)
{
    const int wave = threadIdx.x >> 6;
    const int lane = threadIdx.x & 63;
    const int bag  = blockIdx.x * WAVES_PER_BLOCK + wave;
    if (bag >= NUM_BAGS) return;

    const int t = bag >> 12;              // bag / 4096 (table id, bags table-major)
    const int b = bag & (BPT - 1);

    const int start = offsets[bag];
    const int n     = offsets[bag + 1] - start;

    const int half = lane >> 5;           // 0 -> even rows, 1 -> odd rows
    const int col  = lane & 31;           // float4 column within the 128-dim row

    const float4* __restrict__ tbl =
        reinterpret_cast<const float4*>(weights) + (long long)t * (E * (D / 4));

    float4 a0{0,0,0,0}, a1{0,0,0,0}, a2{0,0,0,0}, a3{0,0,0,0};

    if (n <= 64) {
        // One coalesced index load for the whole bag.
        int myidx = 0;
        if (lane < n) myidx = indices[start + lane];

        int j = 0;
        for (; j + 8 <= n; j += 8) {
            // Row indices via cross-lane broadcast (no memory ops).
            const int r0 = __shfl(myidx, j + 0 + half);
            const int r1 = __shfl(myidx, j + 2 + half);
            const int r2 = __shfl(myidx, j + 4 + half);
            const int r3 = __shfl(myidx, j + 6 + half);
            // 4 independent 1KB gathers in flight.
            const float4 v0 = tbl[(long long)r0 * (D / 4) + col];
            const float4 v1 = tbl[(long long)r1 * (D / 4) + col];
            const float4 v2 = tbl[(long long)r2 * (D / 4) + col];
            const float4 v3 = tbl[(long long)r3 * (D / 4) + col];
            add4(a0, v0); add4(a1, v1); add4(a2, v2); add4(a3, v3);
        }
        if (j + 4 <= n) {
            const int r0 = __shfl(myidx, j + 0 + half);
            const int r1 = __shfl(myidx, j + 2 + half);
            const float4 v0 = tbl[(long long)r0 * (D / 4) + col];
            const float4 v1 = tbl[(long long)r1 * (D / 4) + col];
            add4(a0, v0); add4(a1, v1);
            j += 4;
        }
        if (j + 2 <= n) {
            const int r0 = __shfl(myidx, j + half);
            const float4 v0 = tbl[(long long)r0 * (D / 4) + col];
            add4(a0, v0);
            j += 2;
        }
        if (j < n) {  // odd remainder: only half 0 contributes
            const int r0 = __shfl(myidx, j);
            if (half == 0) {
                const float4 v0 = tbl[(long long)r0 * (D / 4) + col];
                add4(a0, v0);
            }
        }
    } else {
        // Generic ragged fallback (not hit for this benchmark's L=20).
        int j = 0;
        for (; j + 2 <= n; j += 2) {
            const int r = indices[start + j + half];
            const float4 v = tbl[(long long)r * (D / 4) + col];
            add4(a0, v);
        }
        if (j < n) {
            const int r = indices[start + j];
            if (half == 0) {
                const float4 v = tbl[(long long)r * (D / 4) + col];
                add4(a0, v);
            }
        }
    }

    float4 acc;
    acc.x = (a0.x + a1.x) + (a2.x + a3.x);
    acc.y = (a0.y + a1.y) + (a2.y + a3.y);
    acc.z = (a0.z + a1.z) + (a2.z + a3.z);
    acc.w = (a0.w + a1.w) + (a2.w + a3.w);

    // Fold odd-row half into even-row half (and vice versa).
    acc.x += __shfl_xor(acc.x, 32);
    acc.y += __shfl_xor(acc.y, 32);
    acc.z += __shfl_xor(acc.z, 32);
    acc.w += __shfl_xor(acc.w, 32);

    // Store: lanes 0..31 write the full 512B row of out[b, t*D .. t*D+127].
    if (half == 0) {
        float4* __restrict__ o =
            reinterpret_cast<float4*>(out) + (long long)b * (T * D / 4) + t * (D / 4);
        o[col] = acc;
    }
}

extern "C" void kernel_launch(void* const* d_in, const int* in_sizes, int n_in,
                              void* d_out, int out_size, void* d_ws, size_t ws_size,
                              hipStream_t stream) {
    const float* weights = (const float*)d_in[0];
    const int*   indices = (const int*)d_in[1];
    const int*   offsets = (const int*)d_in[2];
    float*       out     = (float*)d_out;

    const int grid = NUM_BAGS / WAVES_PER_BLOCK;  // 16384 blocks x 256 threads
    tbe_pool_kernel<<<grid, 256, 0, stream>>>(weights, indices, offsets, out);
}